// Round 1
// baseline (469.487 us; speedup 1.0000x reference)
//
#include <hip/hip_runtime.h>
#include <hip/hip_bf16.h>
#include <stdint.h>

// ---------- types ----------
typedef __attribute__((ext_vector_type(8))) __bf16 bf16x8;
typedef __attribute__((ext_vector_type(4))) float  f32x4;

#define MFMA16(a, b, c) __builtin_amdgcn_mfma_f32_16x16x32_bf16((a), (b), (c), 0, 0, 0)

// Problem constants
#define BB 4
#define TT 2048
#define CC 1024
#define HH 16
#define DH 64
#define GM 8192   // B*T
#define GN 1024
#define GK 1024

// ---------- fp32 -> bf16 conversion ----------
__global__ __launch_bounds__(256) void cvt_kernel(const float* __restrict__ src,
                                                  __bf16* __restrict__ dst, int n8) {
    int i = blockIdx.x * blockDim.x + threadIdx.x;
    if (i >= n8) return;
    const float4* s = (const float4*)src + (size_t)i * 2;
    float4 f0 = s[0], f1 = s[1];
    bf16x8 h;
    h[0] = (__bf16)f0.x; h[1] = (__bf16)f0.y; h[2] = (__bf16)f0.z; h[3] = (__bf16)f0.w;
    h[4] = (__bf16)f1.x; h[5] = (__bf16)f1.y; h[6] = (__bf16)f1.z; h[7] = (__bf16)f1.w;
    *(bf16x8*)(dst + (size_t)i * 8) = h;
}

__global__ __launch_bounds__(256) void cvt4_kernel(const float* __restrict__ w0,
                                                   const float* __restrict__ w1,
                                                   const float* __restrict__ w2,
                                                   const float* __restrict__ w3,
                                                   __bf16* __restrict__ dst) {
    const float* srcs[4] = {w0, w1, w2, w3};
    const float* src = srcs[blockIdx.z];
    __bf16* d = dst + (size_t)blockIdx.z * CC * CC;
    int i = blockIdx.x * blockDim.x + threadIdx.x;   // < 131072
    const float4* s = (const float4*)src + (size_t)i * 2;
    float4 f0 = s[0], f1 = s[1];
    bf16x8 h;
    h[0] = (__bf16)f0.x; h[1] = (__bf16)f0.y; h[2] = (__bf16)f0.z; h[3] = (__bf16)f0.w;
    h[4] = (__bf16)f1.x; h[5] = (__bf16)f1.y; h[6] = (__bf16)f1.z; h[7] = (__bf16)f1.w;
    *(bf16x8*)(d + (size_t)i * 8) = h;
}

// ---------- NT GEMM: C[m,n] = sum_k A[m,k] * B[n,k] ----------
// 128x128 tile, BK=32, 256 threads = 4 waves in 2x2, each wave 64x64 via 4x4 mfma frags.
__global__ __launch_bounds__(256) void gemm_nt(const __bf16* __restrict__ A,
                                               const __bf16* __restrict__ Bmat,
                                               __bf16* __restrict__ Cbf,
                                               float* __restrict__ Cf,
                                               size_t b_zstride, size_t c_zstride) {
    const __bf16* Bp = Bmat + (size_t)blockIdx.z * b_zstride;
    __shared__ __bf16 As[128 * 32];
    __shared__ __bf16 Bs[128 * 32];
    int tid  = threadIdx.x;
    int lane = tid & 63, w = tid >> 6;
    int wm = w >> 1, wn = w & 1;
    int l15 = lane & 15, q8 = lane >> 4;
    int m0 = blockIdx.y * 128, n0 = blockIdx.x * 128;

    f32x4 zero = {0.f, 0.f, 0.f, 0.f};
    f32x4 acc[4][4];
#pragma unroll
    for (int i = 0; i < 4; i++)
#pragma unroll
        for (int j = 0; j < 4; j++) acc[i][j] = zero;

    // staging: chunk c -> row c>>2, kcol (c&3)*8 ; LDS flat row-major [128][32]
    int c0 = tid, c1 = tid + 256;
    int r0 = c0 >> 2, kc0 = (c0 & 3) * 8;
    int r1 = c1 >> 2, kc1 = (c1 & 3) * 8;
    const __bf16* Ag0 = A  + (size_t)(m0 + r0) * GK + kc0;
    const __bf16* Ag1 = A  + (size_t)(m0 + r1) * GK + kc1;
    const __bf16* Bg0 = Bp + (size_t)(n0 + r0) * GK + kc0;
    const __bf16* Bg1 = Bp + (size_t)(n0 + r1) * GK + kc1;

    for (int k0 = 0; k0 < GK; k0 += 32) {
        uint4 av0 = *(const uint4*)(Ag0 + k0);
        uint4 av1 = *(const uint4*)(Ag1 + k0);
        uint4 bv0 = *(const uint4*)(Bg0 + k0);
        uint4 bv1 = *(const uint4*)(Bg1 + k0);
        __syncthreads();                 // previous iter's LDS reads done
        *(uint4*)(As + c0 * 8) = av0;
        *(uint4*)(As + c1 * 8) = av1;
        *(uint4*)(Bs + c0 * 8) = bv0;
        *(uint4*)(Bs + c1 * 8) = bv1;
        __syncthreads();
        bf16x8 af[4], bf[4];
#pragma unroll
        for (int mt = 0; mt < 4; mt++)
            af[mt] = *(const bf16x8*)(As + (wm * 64 + mt * 16 + l15) * 32 + q8 * 8);
#pragma unroll
        for (int nt = 0; nt < 4; nt++)
            bf[nt] = *(const bf16x8*)(Bs + (wn * 64 + nt * 16 + l15) * 32 + q8 * 8);
#pragma unroll
        for (int mt = 0; mt < 4; mt++)
#pragma unroll
            for (int nt = 0; nt < 4; nt++)
                acc[mt][nt] = MFMA16(af[mt], bf[nt], acc[mt][nt]);
    }

    // epilogue: C/D layout col = lane&15, row = quad*4 + reg  [m89/m91 verified]
#pragma unroll
    for (int mt = 0; mt < 4; mt++) {
        int mrow = m0 + wm * 64 + mt * 16 + q8 * 4;
#pragma unroll
        for (int nt = 0; nt < 4; nt++) {
            int ncol = n0 + wn * 64 + nt * 16 + l15;
            f32x4 v = acc[mt][nt];
            if (Cf) {
                float* p = Cf + (size_t)blockIdx.z * c_zstride + (size_t)mrow * GN + ncol;
                p[0] = v.x; p[GN] = v.y; p[2 * GN] = v.z; p[3 * GN] = v.w;
            } else {
                __bf16* p = Cbf + (size_t)blockIdx.z * c_zstride + (size_t)mrow * GN + ncol;
                p[0] = (__bf16)v.x; p[GN] = (__bf16)v.y;
                p[2 * GN] = (__bf16)v.z; p[3 * GN] = (__bf16)v.w;
            }
        }
    }
}

// ---------- flash attention, causal, bf16 MFMA ----------
// block = (q-tile of 64 rows, one (b,h)); 4 waves, wave w owns q rows w*16..w*16+15.
#define KSS 72   // K/V LDS row stride (144B: 16B-aligned, 2-way banks = free)
#define PSS 88   // P  LDS row stride (176B: 16B-aligned, 2-way banks = free)

__global__ __launch_bounds__(256) void attn_kernel(const __bf16* __restrict__ Qb,
                                                   const __bf16* __restrict__ Kb,
                                                   const __bf16* __restrict__ Vb,
                                                   __bf16* __restrict__ Y) {
    __shared__ __bf16 Ks[64 * KSS];        // [s][d]
    __shared__ __bf16 Vt[64 * KSS];        // [d][s]  (transposed)
    __shared__ __bf16 Ps[4][16 * PSS];     // per-wave P [q][s]

    int tid  = threadIdx.x;
    int lane = tid & 63, w = tid >> 6;
    int l15 = lane & 15, q8 = lane >> 4;
    int qt = 31 - blockIdx.x;              // heavy tiles first
    int bh = blockIdx.y;
    int b  = bh >> 4, h = bh & 15;
    size_t rowbase = (size_t)b * TT;
    const float C_LOG2E = 0.125f * 1.44269504f;   // scale * log2(e)

    // Q fragments in registers (A-layout: m = lane&15, k = quad*8+j)
    int qrow = qt * 64 + w * 16 + l15;
    const __bf16* qp = Qb + ((rowbase + qrow) * CC + h * DH + q8 * 8);
    bf16x8 qa0 = *(const bf16x8*)qp;
    bf16x8 qa1 = *(const bf16x8*)(qp + 32);

    f32x4 zero = {0.f, 0.f, 0.f, 0.f};
    f32x4 O[4];
    float m_i[4], l_i[4];
#pragma unroll
    for (int i = 0; i < 4; i++) { O[i] = zero; m_i[i] = -1e30f; l_i[i] = 0.f; }

    // staging maps
    int ks0 = tid >> 3, kd = (tid & 7) * 8;          // K pass1 rows 0..31
    int ks1 = (tid + 256) >> 3;                      // K pass2 rows 32..63
    int vs  = tid & 63;                              // V: s = lane, dchunk = wave
    int vd0 = w * 8;
    const __bf16* Kbase = Kb + (rowbase * CC + h * DH);
    const __bf16* Vbase = Vb + (rowbase * CC + h * DH);

    for (int j = 0; j <= qt; j++) {
        size_t srow = (size_t)j * 64;
        uint4 kv0 = *(const uint4*)(Kbase + (srow + ks0) * CC + kd);
        uint4 kv1 = *(const uint4*)(Kbase + (srow + ks1) * CC + kd);
        uint4 vv0 = *(const uint4*)(Vbase + (srow + vs) * CC + vd0);
        uint4 vv1 = *(const uint4*)(Vbase + (srow + vs) * CC + vd0 + 32);
        __syncthreads();                 // prev iter's LDS reads done
        *(uint4*)(Ks + ks0 * KSS + kd) = kv0;
        *(uint4*)(Ks + ks1 * KSS + kd) = kv1;
        {
            const __bf16* p0 = (const __bf16*)&vv0;
            const __bf16* p1 = (const __bf16*)&vv1;
#pragma unroll
            for (int e = 0; e < 8; e++) {
                Vt[(vd0 + e) * KSS + vs]      = p0[e];
                Vt[(vd0 + 32 + e) * KSS + vs] = p1[e];
            }
        }
        __syncthreads();

        // S = Q K^T  (B-frag: n=lane&15 -> key row, k=quad*8+j -> d)
        float s2[4][4];
#pragma unroll
        for (int st = 0; st < 4; st++) {
            f32x4 sa = zero;
            bf16x8 b0 = *(const bf16x8*)(Ks + (st * 16 + l15) * KSS + q8 * 8);
            bf16x8 b1 = *(const bf16x8*)(Ks + (st * 16 + l15) * KSS + 32 + q8 * 8);
            sa = MFMA16(qa0, b0, sa);
            sa = MFMA16(qa1, b1, sa);
            s2[st][0] = sa.x; s2[st][1] = sa.y; s2[st][2] = sa.z; s2[st][3] = sa.w;
        }
        bool diag = (j == qt);
#pragma unroll
        for (int st = 0; st < 4; st++)
#pragma unroll
            for (int r = 0; r < 4; r++) {
                float v = s2[st][r] * C_LOG2E;
                if (diag && (st * 16 + l15) > (w * 16 + q8 * 4 + r)) v = -1e30f;
                s2[st][r] = v;
            }

        // online softmax (rows live on 16-lane groups sharing q8)
        float p[4][4], alpha[4];
#pragma unroll
        for (int r = 0; r < 4; r++) {
            float mx = fmaxf(fmaxf(s2[0][r], s2[1][r]), fmaxf(s2[2][r], s2[3][r]));
#pragma unroll
            for (int mm = 1; mm < 16; mm <<= 1) mx = fmaxf(mx, __shfl_xor(mx, mm, 64));
            float mnew = fmaxf(m_i[r], mx);
            alpha[r] = exp2f(m_i[r] - mnew);
            m_i[r] = mnew;
            float rs = 0.f;
#pragma unroll
            for (int st = 0; st < 4; st++) {
                float pv = exp2f(s2[st][r] - mnew);
                p[st][r] = pv; rs += pv;
            }
#pragma unroll
            for (int mm = 1; mm < 16; mm <<= 1) rs += __shfl_xor(rs, mm, 64);
            l_i[r] = l_i[r] * alpha[r] + rs;
        }
#pragma unroll
        for (int dt = 0; dt < 4; dt++) {
            O[dt].x *= alpha[0]; O[dt].y *= alpha[1];
            O[dt].z *= alpha[2]; O[dt].w *= alpha[3];
        }
        // P: C-layout -> LDS [q][s] (A-layout source for PV)
#pragma unroll
        for (int r = 0; r < 4; r++)
#pragma unroll
            for (int st = 0; st < 4; st++)
                Ps[w][(q8 * 4 + r) * PSS + st * 16 + l15] = (__bf16)p[st][r];

        // O += P V   (A-frag: P[q=lane&15][s-chunk]; B-frag: Vt[d=lane&15][s-chunk])
        bf16x8 ap0 = *(const bf16x8*)(&Ps[w][l15 * PSS + q8 * 8]);
        bf16x8 ap1 = *(const bf16x8*)(&Ps[w][l15 * PSS + 32 + q8 * 8]);
#pragma unroll
        for (int dt = 0; dt < 4; dt++) {
            bf16x8 b0 = *(const bf16x8*)(Vt + (dt * 16 + l15) * KSS + q8 * 8);
            bf16x8 b1 = *(const bf16x8*)(Vt + (dt * 16 + l15) * KSS + 32 + q8 * 8);
            O[dt] = MFMA16(ap0, b0, O[dt]);
            O[dt] = MFMA16(ap1, b1, O[dt]);
        }
    }

    float rinv[4];
#pragma unroll
    for (int r = 0; r < 4; r++) rinv[r] = 1.f / l_i[r];
#pragma unroll
    for (int dt = 0; dt < 4; dt++) {
        int col = h * DH + dt * 16 + l15;
        __bf16* yp = Y + (rowbase + qt * 64 + w * 16 + q8 * 4) * CC + col;
        yp[0]        = (__bf16)(O[dt].x * rinv[0]);
        yp[CC]       = (__bf16)(O[dt].y * rinv[1]);
        yp[2 * CC]   = (__bf16)(O[dt].z * rinv[2]);
        yp[3 * CC]   = (__bf16)(O[dt].w * rinv[3]);
    }
}

// ---------- launch ----------
extern "C" void kernel_launch(void* const* d_in, const int* in_sizes, int n_in,
                              void* d_out, int out_size, void* d_ws, size_t ws_size,
                              hipStream_t stream) {
    const float* x  = (const float*)d_in[0];
    const float* wq = (const float*)d_in[1];
    const float* wk = (const float*)d_in[2];
    const float* wv = (const float*)d_in[3];
    const float* wo = (const float*)d_in[4];
    float* out = (float*)d_out;

    char* ws = (char*)d_ws;
    __bf16* xb  = (__bf16*)ws;                              // 8192x1024 bf16 (16 MB)
    __bf16* wb  = (__bf16*)(ws + (size_t)16777216);         // 4x1024x1024 bf16 (8 MB)
    __bf16* qkv = (__bf16*)(ws + (size_t)25165824);         // 3x8192x1024 bf16 (48 MB)
    __bf16* yb  = (__bf16*)(ws + (size_t)75497472);         // 8192x1024 bf16 (16 MB)

    cvt_kernel<<<dim3(GM * GK / 8 / 256), 256, 0, stream>>>(x, xb, GM * GK / 8);
    cvt4_kernel<<<dim3(CC * CC / 8 / 256, 1, 4), 256, 0, stream>>>(wq, wk, wv, wo, wb);
    // QKV: z selects {wq,wk,wv}; output z-stride = one [8192,1024] plane
    gemm_nt<<<dim3(GN / 128, GM / 128, 3), 256, 0, stream>>>(
        xb, wb, qkv, nullptr, (size_t)CC * CC, (size_t)GM * GN);
    attn_kernel<<<dim3(32, BB * HH), 256, 0, stream>>>(
        qkv, qkv + (size_t)GM * GN, qkv + (size_t)2 * GM * GN, yb);
    // output projection: fp32 out
    gemm_nt<<<dim3(GN / 128, GM / 128, 1), 256, 0, stream>>>(
        yb, wb + (size_t)3 * CC * CC, nullptr, out, 0, 0);
}

// Round 2
// 407.505 us; speedup vs baseline: 1.1521x; 1.1521x over previous
//
#include <hip/hip_runtime.h>
#include <hip/hip_bf16.h>
#include <stdint.h>

// ---------- types ----------
typedef __attribute__((ext_vector_type(8))) __bf16 bf16x8;
typedef __attribute__((ext_vector_type(4))) __bf16 bf16x4;
typedef __attribute__((ext_vector_type(4))) float  f32x4;

#define MFMA16(a, b, c) __builtin_amdgcn_mfma_f32_16x16x32_bf16((a), (b), (c), 0, 0, 0)

// async global->LDS, 16B per lane; LDS dest = wave-uniform base + lane*16
#define GLD16(gp, lp) __builtin_amdgcn_global_load_lds(                                   \
    (const __attribute__((address_space(1))) uint32_t*)(gp),                              \
    (__attribute__((address_space(3))) uint32_t*)(lp), 16, 0, 0)

// Problem constants
#define BB 4
#define TT 2048
#define CC 1024
#define HH 16
#define DH 64
#define GM 8192   // B*T
#define GN 1024
#define GK 1024

// ---------- fp32 -> bf16 conversion ----------
__global__ __launch_bounds__(256) void cvt_kernel(const float* __restrict__ src,
                                                  __bf16* __restrict__ dst, int n8) {
    int i = blockIdx.x * blockDim.x + threadIdx.x;
    if (i >= n8) return;
    const float4* s = (const float4*)src + (size_t)i * 2;
    float4 f0 = s[0], f1 = s[1];
    bf16x8 h;
    h[0] = (__bf16)f0.x; h[1] = (__bf16)f0.y; h[2] = (__bf16)f0.z; h[3] = (__bf16)f0.w;
    h[4] = (__bf16)f1.x; h[5] = (__bf16)f1.y; h[6] = (__bf16)f1.z; h[7] = (__bf16)f1.w;
    *(bf16x8*)(dst + (size_t)i * 8) = h;
}

__global__ __launch_bounds__(256) void cvt4_kernel(const float* __restrict__ w0,
                                                   const float* __restrict__ w1,
                                                   const float* __restrict__ w2,
                                                   const float* __restrict__ w3,
                                                   __bf16* __restrict__ dst) {
    const float* srcs[4] = {w0, w1, w2, w3};
    const float* src = srcs[blockIdx.z];
    __bf16* d = dst + (size_t)blockIdx.z * CC * CC;
    int i = blockIdx.x * blockDim.x + threadIdx.x;
    const float4* s = (const float4*)src + (size_t)i * 2;
    float4 f0 = s[0], f1 = s[1];
    bf16x8 h;
    h[0] = (__bf16)f0.x; h[1] = (__bf16)f0.y; h[2] = (__bf16)f0.z; h[3] = (__bf16)f0.w;
    h[4] = (__bf16)f1.x; h[5] = (__bf16)f1.y; h[6] = (__bf16)f1.z; h[7] = (__bf16)f1.w;
    *(bf16x8*)(d + (size_t)i * 8) = h;
}

// ---------- bf16 transpose: V [8192][1024] -> VT [1024][8192] ----------
__global__ __launch_bounds__(256) void transpose_kernel(const __bf16* __restrict__ V,
                                                        __bf16* __restrict__ VT) {
    __shared__ __bf16 Ts[64][72];  // +8 pad
    int tid = threadIdx.x;
    int m0 = blockIdx.x * 64, c0 = blockIdx.y * 64;
#pragma unroll
    for (int r = 0; r < 2; r++) {
        int ch = r * 256 + tid;
        int mm = ch >> 3, c8 = (ch & 7) * 8;
        *(uint4*)&Ts[mm][c8] = *(const uint4*)(V + (size_t)(m0 + mm) * CC + c0 + c8);
    }
    __syncthreads();
#pragma unroll
    for (int r = 0; r < 2; r++) {
        int ch = r * 256 + tid;
        int cc = ch >> 3, m8 = (ch & 7) * 8;
        bf16x8 v;
#pragma unroll
        for (int e = 0; e < 8; e++) v[e] = Ts[m8 + e][cc];
        *(bf16x8*)(VT + (size_t)(c0 + cc) * GM + m0 + m8) = v;
    }
}

// ---------- NT GEMM: C[m,n] = sum_k A[m,k] * B[n,k] ----------
// 128x128 tile, BK=32, global_load_lds width-16 staging (m97 structure).
__global__ __launch_bounds__(256) void gemm_nt(const __bf16* __restrict__ A,
                                               const __bf16* __restrict__ Bmat,
                                               __bf16* __restrict__ Cbf,
                                               float* __restrict__ Cf,
                                               size_t b_zstride, size_t c_zstride) {
    const __bf16* Bp = Bmat + (size_t)blockIdx.z * b_zstride;
    __shared__ __bf16 As[128 * 32];
    __shared__ __bf16 Bs[128 * 32];
    int tid  = threadIdx.x;
    int lane = tid & 63, w = tid >> 6;
    int wm = w >> 1, wn = w & 1;
    int l15 = lane & 15, q8 = lane >> 4;
    int m0 = blockIdx.y * 128, n0 = blockIdx.x * 128;

    f32x4 zero = {0.f, 0.f, 0.f, 0.f};
    f32x4 acc[4][4];
#pragma unroll
    for (int i = 0; i < 4; i++)
#pragma unroll
        for (int j = 0; j < 4; j++) acc[i][j] = zero;

    // staging chunk c -> LDS byte c*16 == (row c>>2, kcol (c&3)*8); lane-ordered.
    int c0 = tid, c1 = tid + 256;
    const __bf16* Ag0 = A  + (size_t)(m0 + (c0 >> 2)) * GK + (c0 & 3) * 8;
    const __bf16* Ag1 = A  + (size_t)(m0 + (c1 >> 2)) * GK + (c1 & 3) * 8;
    const __bf16* Bg0 = Bp + (size_t)(n0 + (c0 >> 2)) * GK + (c0 & 3) * 8;
    const __bf16* Bg1 = Bp + (size_t)(n0 + (c1 >> 2)) * GK + (c1 & 3) * 8;
    char* AsB = (char*)As; char* BsB = (char*)Bs;
    int wbase = (tid & ~63) * 16;   // wave-uniform chunk base (bytes)

    for (int k0 = 0; k0 < GK; k0 += 32) {
        __syncthreads();                 // prev iter's LDS reads done
        GLD16(Ag0 + k0, AsB + wbase);
        GLD16(Ag1 + k0, AsB + 4096 + wbase);
        GLD16(Bg0 + k0, BsB + wbase);
        GLD16(Bg1 + k0, BsB + 4096 + wbase);
        __syncthreads();                 // vmcnt drained before barrier -> staged
        bf16x8 af[4], bf[4];
#pragma unroll
        for (int mt = 0; mt < 4; mt++)
            af[mt] = *(const bf16x8*)(As + (wm * 64 + mt * 16 + l15) * 32 + q8 * 8);
#pragma unroll
        for (int nt = 0; nt < 4; nt++)
            bf[nt] = *(const bf16x8*)(Bs + (wn * 64 + nt * 16 + l15) * 32 + q8 * 8);
#pragma unroll
        for (int mt = 0; mt < 4; mt++)
#pragma unroll
            for (int nt = 0; nt < 4; nt++)
                acc[mt][nt] = MFMA16(af[mt], bf[nt], acc[mt][nt]);
    }

    // epilogue: C/D layout col = lane&15 (n), row = quad*4 + reg (m)
#pragma unroll
    for (int mt = 0; mt < 4; mt++) {
        int mrow = m0 + wm * 64 + mt * 16 + q8 * 4;
#pragma unroll
        for (int nt = 0; nt < 4; nt++) {
            int ncol = n0 + wn * 64 + nt * 16 + l15;
            f32x4 v = acc[mt][nt];
            if (Cf) {
                float* p = Cf + (size_t)blockIdx.z * c_zstride + (size_t)mrow * GN + ncol;
                p[0] = v.x; p[GN] = v.y; p[2 * GN] = v.z; p[3 * GN] = v.w;
            } else {
                __bf16* p = Cbf + (size_t)blockIdx.z * c_zstride + (size_t)mrow * GN + ncol;
                p[0] = (__bf16)v.x; p[GN] = (__bf16)v.y;
                p[2 * GN] = (__bf16)v.z; p[3 * GN] = (__bf16)v.w;
            }
        }
    }
}

// ---------- flash attention, causal, S^T formulation ----------
// Block: 128 q-rows (2 strips of 64; wave w owns q = strip + w*16+l15), K-tile 64.
// S^T = K.Q^T  (A=K tile: m=s, B=Q: n=q) -> P^T C-layout regs are 4 consecutive s
// at fixed q => b64 P stores. Row softmax is per-lane + 2 shuffles. Row-sum folds
// into PV via a ones A-fragment (l accumulates in acc[*][4] under the same alpha).
// K and V^T staged via global_load_lds with XOR-swizzled 16B chunks (bank-balanced).
__global__ __launch_bounds__(256) void attn_kernel(const __bf16* __restrict__ Q,
                                                   const __bf16* __restrict__ K,
                                                   const __bf16* __restrict__ VT,
                                                   __bf16* __restrict__ Y) {
    __shared__ __bf16 Ks[64 * 64];     // [s][d], chunk-swizzled
    __shared__ __bf16 Vs[64 * 64];     // [d][s], chunk-swizzled
    __shared__ __bf16 Ps[4][16 * 64];  // per-wave P [q][s], chunk-swizzled

    int tid  = threadIdx.x;
    int lane = tid & 63, w = tid >> 6;
    int l15 = lane & 15, q8 = lane >> 4;
    int qt = 15 - blockIdx.x;          // heavy tiles dispatch first
    int bh = blockIdx.y, b = bh >> 4, h = bh & 15;
    size_t rowb = (size_t)b * TT;
    const float SC = 0.125f * 1.44269504f;   // scale * log2(e)
    int ql = w * 16 + l15;             // q offset within diag tile
    int x7 = l15 & 7;                  // xor-swizzle key (row & 7)

    // Q B-frags (n = q = l15-row of strip, k = d = kc*32 + q8*8 + j)
    bf16x8 qfr[2][2];
#pragma unroll
    for (int qf = 0; qf < 2; qf++) {
        int q = qt * 128 + qf * 64 + w * 16 + l15;
        const __bf16* qp = Q + (rowb + q) * CC + h * DH + q8 * 8;
        qfr[qf][0] = *(const bf16x8*)qp;
        qfr[qf][1] = *(const bf16x8*)(qp + 32);
    }

    f32x4 zero = {0.f, 0.f, 0.f, 0.f};
    f32x4 acc[2][5];
    float m_i[2] = {-1e30f, -1e30f};
#pragma unroll
    for (int qf = 0; qf < 2; qf++)
#pragma unroll
        for (int t5 = 0; t5 < 5; t5++) acc[qf][t5] = zero;

    // ones A-frag: A[m][k] = (m==0) -> row 0 of dt=4 tile = sum_s P^T[s][q]
    bf16x8 ones;
#pragma unroll
    for (int e = 0; e < 8; e++) ones[e] = (l15 == 0) ? (__bf16)1.0f : (__bf16)0.0f;

    // staging: chunk c -> (row c>>3, swizzled col-chunk c&7); inverse-swizzle the
    // global fetch so LDS chunk (r, c8) holds global (r, c8 ^ (r&7)).
    int c0 = tid, c1 = tid + 256;
    int s0 = c0 >> 3, d80 = ((c0 & 7) ^ (s0 & 7)) * 8;
    int s1 = c1 >> 3, d81 = ((c1 & 7) ^ (s1 & 7)) * 8;
    const __bf16* Kg0 = K + (rowb + s0) * CC + h * DH + d80;
    const __bf16* Kg1 = K + (rowb + s1) * CC + h * DH + d81;
    const __bf16* Vg0 = VT + (size_t)(h * DH + s0) * GM + rowb + d80;
    const __bf16* Vg1 = VT + (size_t)(h * DH + s1) * GM + rowb + d81;
    char* KsB = (char*)Ks; char* VsB = (char*)Vs;
    int wbase = (tid & ~63) * 16;

    int jmax = 2 * qt + 1;
    for (int j = 0; j <= jmax; j++) {
        __syncthreads();                 // prev iter's LDS reads done
        GLD16(Kg0 + (size_t)j * 64 * CC, KsB + wbase);
        GLD16(Kg1 + (size_t)j * 64 * CC, KsB + 4096 + wbase);
        GLD16(Vg0 + j * 64, VsB + wbase);
        GLD16(Vg1 + j * 64, VsB + 4096 + wbase);
        __syncthreads();

        bool do0 = (j != jmax);          // strip 0 fully masked on the last k-tile

        // S^T: per st tile, A = K rows (m=s), B = Q (n=q)
        f32x4 s2[2][4];
#pragma unroll
        for (int st = 0; st < 4; st++) {
            bf16x8 k0f = *(const bf16x8*)(Ks + (st * 16 + l15) * 64 + ((q8 ^ x7) * 8));
            bf16x8 k1f = *(const bf16x8*)(Ks + (st * 16 + l15) * 64 + (((q8 + 4) ^ x7) * 8));
            if (do0) {
                f32x4 t = zero;
                t = MFMA16(k0f, qfr[0][0], t);
                t = MFMA16(k1f, qfr[0][1], t);
                s2[0][st] = t;
            }
            f32x4 t = zero;
            t = MFMA16(k0f, qfr[1][0], t);
            t = MFMA16(k1f, qfr[1][1], t);
            s2[1][st] = t;
        }

        // softmax + P write + acc rescale, per strip
        bf16x8 bp[2][2];
#pragma unroll
        for (int qf = 0; qf < 2; qf++) {
            if (qf == 0 && !do0) continue;
            bool diag = (j == 2 * qt + qf);
            float mx = -1e30f;
#pragma unroll
            for (int st = 0; st < 4; st++) {
                f32x4 t = s2[qf][st] * SC;
                if (diag) {
                    int sb = st * 16 + q8 * 4;
                    if (sb + 0 > ql) t.x = -1e30f;
                    if (sb + 1 > ql) t.y = -1e30f;
                    if (sb + 2 > ql) t.z = -1e30f;
                    if (sb + 3 > ql) t.w = -1e30f;
                }
                s2[qf][st] = t;
                mx = fmaxf(mx, fmaxf(fmaxf(t.x, t.y), fmaxf(t.z, t.w)));
            }
            mx = fmaxf(mx, __shfl_xor(mx, 16));
            mx = fmaxf(mx, __shfl_xor(mx, 32));
            float mnew = fmaxf(m_i[qf], mx);
            float alpha = exp2f(m_i[qf] - mnew);
            m_i[qf] = mnew;
#pragma unroll
            for (int st = 0; st < 4; st++) {
                bf16x4 pk;
                pk[0] = (__bf16)exp2f(s2[qf][st].x - mnew);
                pk[1] = (__bf16)exp2f(s2[qf][st].y - mnew);
                pk[2] = (__bf16)exp2f(s2[qf][st].z - mnew);
                pk[3] = (__bf16)exp2f(s2[qf][st].w - mnew);
                int swzc = (st * 2 + (q8 >> 1)) ^ x7;
                *(bf16x4*)(Ps[w] + l15 * 64 + swzc * 8 + (q8 & 1) * 4) = pk;
            }
#pragma unroll
            for (int t5 = 0; t5 < 5; t5++) acc[qf][t5] = acc[qf][t5] * alpha;
            // read this strip's P B-frags before the other strip overwrites Ps[w]
            bp[qf][0] = *(const bf16x8*)(Ps[w] + l15 * 64 + ((q8 ^ x7) * 8));
            bp[qf][1] = *(const bf16x8*)(Ps[w] + l15 * 64 + (((q8 + 4) ^ x7) * 8));
        }

        // O^T += V^T P^T  (A = V^T rows m=d, B = P^T n=q)
#pragma unroll
        for (int dt = 0; dt < 4; dt++) {
            bf16x8 v0 = *(const bf16x8*)(Vs + (dt * 16 + l15) * 64 + ((q8 ^ x7) * 8));
            bf16x8 v1 = *(const bf16x8*)(Vs + (dt * 16 + l15) * 64 + (((q8 + 4) ^ x7) * 8));
            if (do0) {
                acc[0][dt] = MFMA16(v0, bp[0][0], acc[0][dt]);
                acc[0][dt] = MFMA16(v1, bp[0][1], acc[0][dt]);
            }
            acc[1][dt] = MFMA16(v0, bp[1][0], acc[1][dt]);
            acc[1][dt] = MFMA16(v1, bp[1][1], acc[1][dt]);
        }
        if (do0) {
            acc[0][4] = MFMA16(ones, bp[0][0], acc[0][4]);
            acc[0][4] = MFMA16(ones, bp[0][1], acc[0][4]);
        }
        acc[1][4] = MFMA16(ones, bp[1][0], acc[1][4]);
        acc[1][4] = MFMA16(ones, bp[1][1], acc[1][4]);
    }

    // epilogue: O^T C-layout col=l15=q, row=q8*4+r=d; l sits in acc[*][4].x at lane l15
#pragma unroll
    for (int qf = 0; qf < 2; qf++) {
        float lsum = __shfl(acc[qf][4].x, l15);
        float ri = 1.0f / lsum;
        int q = qt * 128 + qf * 64 + w * 16 + l15;
        __bf16* yp = Y + (rowb + q) * CC + h * DH + q8 * 4;
#pragma unroll
        for (int dt = 0; dt < 4; dt++) {
            bf16x4 o;
            o[0] = (__bf16)(acc[qf][dt].x * ri);
            o[1] = (__bf16)(acc[qf][dt].y * ri);
            o[2] = (__bf16)(acc[qf][dt].z * ri);
            o[3] = (__bf16)(acc[qf][dt].w * ri);
            *(bf16x4*)(yp + dt * 16) = o;
        }
    }
}

// ---------- launch ----------
extern "C" void kernel_launch(void* const* d_in, const int* in_sizes, int n_in,
                              void* d_out, int out_size, void* d_ws, size_t ws_size,
                              hipStream_t stream) {
    const float* x  = (const float*)d_in[0];
    const float* wq = (const float*)d_in[1];
    const float* wk = (const float*)d_in[2];
    const float* wv = (const float*)d_in[3];
    const float* wo = (const float*)d_in[4];
    float* out = (float*)d_out;

    char* ws = (char*)d_ws;
    __bf16* xb  = (__bf16*)ws;                              // [0,16M): xb, then VT after QKV GEMM
    __bf16* wb  = (__bf16*)(ws + (size_t)16777216);         // [16M,24M): 4 weights bf16
    __bf16* qkv = (__bf16*)(ws + (size_t)25165824);         // [24M,72M): Q,K,V planes
    __bf16* yb  = (__bf16*)(ws + (size_t)75497472);         // [72M,88M): attn out bf16

    cvt_kernel<<<dim3(GM * GK / 8 / 256), 256, 0, stream>>>(x, xb, GM * GK / 8);
    cvt4_kernel<<<dim3(CC * CC / 8 / 256, 1, 4), 256, 0, stream>>>(wq, wk, wv, wo, wb);
    gemm_nt<<<dim3(GN / 128, GM / 128, 3), 256, 0, stream>>>(
        xb, wb, qkv, nullptr, (size_t)CC * CC, (size_t)GM * GN);
    // V plane -> VT [1024][8192]; xb region is dead now, reuse it
    transpose_kernel<<<dim3(GM / 64, GN / 64), 256, 0, stream>>>(
        qkv + (size_t)2 * GM * GN, xb);
    attn_kernel<<<dim3(16, BB * HH), 256, 0, stream>>>(
        qkv, qkv + (size_t)GM * GN, xb, yb);
    gemm_nt<<<dim3(GN / 128, GM / 128, 1), 256, 0, stream>>>(
        yb, wb + (size_t)3 * CC * CC, nullptr, out, 0, 0);
}

// Round 3
// 371.968 us; speedup vs baseline: 1.2622x; 1.0955x over previous
//
#include <hip/hip_runtime.h>
#include <hip/hip_bf16.h>
#include <stdint.h>

// ---------- types ----------
typedef __attribute__((ext_vector_type(8))) __bf16 bf16x8;
typedef __attribute__((ext_vector_type(4))) __bf16 bf16x4;
typedef __attribute__((ext_vector_type(4))) float  f32x4;

#define MFMA16(a, b, c) __builtin_amdgcn_mfma_f32_16x16x32_bf16((a), (b), (c), 0, 0, 0)

// async global->LDS, 16B per lane; LDS dest = wave-uniform base + lane*16
#define GLD16(gp, lp) __builtin_amdgcn_global_load_lds(                                   \
    (const __attribute__((address_space(1))) uint32_t*)(gp),                              \
    (__attribute__((address_space(3))) uint32_t*)(lp), 16, 0, 0)

// Problem constants
#define BB 4
#define TT 2048
#define CC 1024
#define HH 16
#define DH 64
#define GM 8192   // B*T
#define GN 1024
#define GK 1024

// ---------- fp32 -> bf16 conversion ----------
__global__ __launch_bounds__(256) void cvt_kernel(const float* __restrict__ src,
                                                  __bf16* __restrict__ dst, int n8) {
    int i = blockIdx.x * blockDim.x + threadIdx.x;
    if (i >= n8) return;
    const float4* s = (const float4*)src + (size_t)i * 2;
    float4 f0 = s[0], f1 = s[1];
    bf16x8 h;
    h[0] = (__bf16)f0.x; h[1] = (__bf16)f0.y; h[2] = (__bf16)f0.z; h[3] = (__bf16)f0.w;
    h[4] = (__bf16)f1.x; h[5] = (__bf16)f1.y; h[6] = (__bf16)f1.z; h[7] = (__bf16)f1.w;
    *(bf16x8*)(dst + (size_t)i * 8) = h;
}

__global__ __launch_bounds__(256) void cvt4_kernel(const float* __restrict__ w0,
                                                   const float* __restrict__ w1,
                                                   const float* __restrict__ w2,
                                                   const float* __restrict__ w3,
                                                   __bf16* __restrict__ dst) {
    const float* srcs[4] = {w0, w1, w2, w3};
    const float* src = srcs[blockIdx.z];
    __bf16* d = dst + (size_t)blockIdx.z * CC * CC;
    int i = blockIdx.x * blockDim.x + threadIdx.x;
    const float4* s = (const float4*)src + (size_t)i * 2;
    float4 f0 = s[0], f1 = s[1];
    bf16x8 h;
    h[0] = (__bf16)f0.x; h[1] = (__bf16)f0.y; h[2] = (__bf16)f0.z; h[3] = (__bf16)f0.w;
    h[4] = (__bf16)f1.x; h[5] = (__bf16)f1.y; h[6] = (__bf16)f1.z; h[7] = (__bf16)f1.w;
    *(bf16x8*)(d + (size_t)i * 8) = h;
}

// ---------- bf16 transpose: V [8192][1024] -> VT [1024][8192] ----------
__global__ __launch_bounds__(256) void transpose_kernel(const __bf16* __restrict__ V,
                                                        __bf16* __restrict__ VT) {
    __shared__ __bf16 Ts[64][72];  // +8 pad
    int tid = threadIdx.x;
    int m0 = blockIdx.x * 64, c0 = blockIdx.y * 64;
#pragma unroll
    for (int r = 0; r < 2; r++) {
        int ch = r * 256 + tid;
        int mm = ch >> 3, c8 = (ch & 7) * 8;
        *(uint4*)&Ts[mm][c8] = *(const uint4*)(V + (size_t)(m0 + mm) * CC + c0 + c8);
    }
    __syncthreads();
#pragma unroll
    for (int r = 0; r < 2; r++) {
        int ch = r * 256 + tid;
        int cc = ch >> 3, m8 = (ch & 7) * 8;
        bf16x8 v;
#pragma unroll
        for (int e = 0; e < 8; e++) v[e] = Ts[m8 + e][cc];
        *(bf16x8*)(VT + (size_t)(c0 + cc) * GM + m0 + m8) = v;
    }
}

// ---------- NT GEMM: C[m,n] = sum_k A[m,k] * B[n,k] ----------
// 128x128 tile, BK=32, global_load_lds width-16 staging (m97 structure).
__global__ __launch_bounds__(256) void gemm_nt(const __bf16* __restrict__ A,
                                               const __bf16* __restrict__ Bmat,
                                               __bf16* __restrict__ Cbf,
                                               float* __restrict__ Cf,
                                               size_t b_zstride, size_t c_zstride) {
    const __bf16* Bp = Bmat + (size_t)blockIdx.z * b_zstride;
    __shared__ __bf16 As[128 * 32];
    __shared__ __bf16 Bs[128 * 32];
    int tid  = threadIdx.x;
    int lane = tid & 63, w = tid >> 6;
    int wm = w >> 1, wn = w & 1;
    int l15 = lane & 15, q8 = lane >> 4;
    int m0 = blockIdx.y * 128, n0 = blockIdx.x * 128;

    f32x4 zero = {0.f, 0.f, 0.f, 0.f};
    f32x4 acc[4][4];
#pragma unroll
    for (int i = 0; i < 4; i++)
#pragma unroll
        for (int j = 0; j < 4; j++) acc[i][j] = zero;

    // staging chunk c -> LDS byte c*16 == (row c>>2, kcol (c&3)*8); lane-ordered.
    int c0 = tid, c1 = tid + 256;
    const __bf16* Ag0 = A  + (size_t)(m0 + (c0 >> 2)) * GK + (c0 & 3) * 8;
    const __bf16* Ag1 = A  + (size_t)(m0 + (c1 >> 2)) * GK + (c1 & 3) * 8;
    const __bf16* Bg0 = Bp + (size_t)(n0 + (c0 >> 2)) * GK + (c0 & 3) * 8;
    const __bf16* Bg1 = Bp + (size_t)(n0 + (c1 >> 2)) * GK + (c1 & 3) * 8;
    char* AsB = (char*)As; char* BsB = (char*)Bs;
    int wbase = (tid & ~63) * 16;   // wave-uniform chunk base (bytes)

    for (int k0 = 0; k0 < GK; k0 += 32) {
        __syncthreads();                 // prev iter's LDS reads done
        GLD16(Ag0 + k0, AsB + wbase);
        GLD16(Ag1 + k0, AsB + 4096 + wbase);
        GLD16(Bg0 + k0, BsB + wbase);
        GLD16(Bg1 + k0, BsB + 4096 + wbase);
        __syncthreads();                 // vmcnt drained before barrier -> staged
        bf16x8 af[4], bf[4];
#pragma unroll
        for (int mt = 0; mt < 4; mt++)
            af[mt] = *(const bf16x8*)(As + (wm * 64 + mt * 16 + l15) * 32 + q8 * 8);
#pragma unroll
        for (int nt = 0; nt < 4; nt++)
            bf[nt] = *(const bf16x8*)(Bs + (wn * 64 + nt * 16 + l15) * 32 + q8 * 8);
#pragma unroll
        for (int mt = 0; mt < 4; mt++)
#pragma unroll
            for (int nt = 0; nt < 4; nt++)
                acc[mt][nt] = MFMA16(af[mt], bf[nt], acc[mt][nt]);
    }

    // epilogue: C/D layout col = lane&15 (n), row = quad*4 + reg (m)
#pragma unroll
    for (int mt = 0; mt < 4; mt++) {
        int mrow = m0 + wm * 64 + mt * 16 + q8 * 4;
#pragma unroll
        for (int nt = 0; nt < 4; nt++) {
            int ncol = n0 + wn * 64 + nt * 16 + l15;
            f32x4 v = acc[mt][nt];
            if (Cf) {
                float* p = Cf + (size_t)blockIdx.z * c_zstride + (size_t)mrow * GN + ncol;
                p[0] = v.x; p[GN] = v.y; p[2 * GN] = v.z; p[3 * GN] = v.w;
            } else {
                __bf16* p = Cbf + (size_t)blockIdx.z * c_zstride + (size_t)mrow * GN + ncol;
                p[0] = (__bf16)v.x; p[GN] = (__bf16)v.y;
                p[2 * GN] = (__bf16)v.z; p[3 * GN] = (__bf16)v.w;
            }
        }
    }
}

// ---------- flash attention, causal, S^T formulation, double-buffered ----------
// Block: 128 q-rows (2 strips of 64), K-tile 64, K/V LDS double-buffered so
// GLD(j+1) latency overlaps compute(j); ONE barrier per k-tile.
// Q pre-scaled by scale*log2e at fragment load; exp2 via raw v_exp_f32.
__global__ __launch_bounds__(256) void attn_kernel(const __bf16* __restrict__ Q,
                                                   const __bf16* __restrict__ K,
                                                   const __bf16* __restrict__ VT,
                                                   __bf16* __restrict__ Y) {
    __shared__ __bf16 Ks[2][64 * 64];  // [s][d], chunk-swizzled, dbuf
    __shared__ __bf16 Vs[2][64 * 64];  // [d][s], chunk-swizzled, dbuf
    __shared__ __bf16 Ps[4][16 * 64];  // per-wave P [q][s], chunk-swizzled

    int tid  = threadIdx.x;
    int lane = tid & 63, w = tid >> 6;
    int l15 = lane & 15, q8 = lane >> 4;
    int qt = 15 - blockIdx.x;          // heavy tiles dispatch first
    int bh = blockIdx.y, b = bh >> 4, h = bh & 15;
    size_t rowb = (size_t)b * TT;
    const float SC = 0.125f * 1.44269504f;   // scale * log2(e), folded into Q
    int ql = w * 16 + l15;             // q offset within diag tile
    int x7 = l15 & 7;                  // xor-swizzle key (row & 7)

    // Q B-frags (n = q, k = d), pre-scaled by SC (once per block, not per iter)
    bf16x8 qfr[2][2];
#pragma unroll
    for (int qf = 0; qf < 2; qf++) {
        int q = qt * 128 + qf * 64 + w * 16 + l15;
        const __bf16* qp = Q + (rowb + q) * CC + h * DH + q8 * 8;
        bf16x8 r0 = *(const bf16x8*)qp;
        bf16x8 r1 = *(const bf16x8*)(qp + 32);
#pragma unroll
        for (int e = 0; e < 8; e++) {
            r0[e] = (__bf16)((float)r0[e] * SC);
            r1[e] = (__bf16)((float)r1[e] * SC);
        }
        qfr[qf][0] = r0; qfr[qf][1] = r1;
    }

    f32x4 zero = {0.f, 0.f, 0.f, 0.f};
    f32x4 acc[2][5];
    float m_i[2] = {-1e30f, -1e30f};
#pragma unroll
    for (int qf = 0; qf < 2; qf++)
#pragma unroll
        for (int t5 = 0; t5 < 5; t5++) acc[qf][t5] = zero;

    // ones A-frag: row 0 of dt=4 tile accumulates l = sum_s P^T[s][q]
    bf16x8 ones;
#pragma unroll
    for (int e = 0; e < 8; e++) ones[e] = (l15 == 0) ? (__bf16)1.0f : (__bf16)0.0f;

    // staging: chunk c -> (row c>>3, swizzled col-chunk c&7)
    int c0 = tid, c1 = tid + 256;
    int s0 = c0 >> 3, d80 = ((c0 & 7) ^ (s0 & 7)) * 8;
    int s1 = c1 >> 3, d81 = ((c1 & 7) ^ (s1 & 7)) * 8;
    const __bf16* Kg0 = K + (rowb + s0) * CC + h * DH + d80;
    const __bf16* Kg1 = K + (rowb + s1) * CC + h * DH + d81;
    const __bf16* Vg0 = VT + (size_t)(h * DH + s0) * GM + rowb + d80;
    const __bf16* Vg1 = VT + (size_t)(h * DH + s1) * GM + rowb + d81;
    char* KsB = (char*)Ks; char* VsB = (char*)Vs;
    int wbase = (tid & ~63) * 16;

    // prologue: stage tile 0 into buffer 0
    GLD16(Kg0, KsB + wbase);
    GLD16(Kg1, KsB + 4096 + wbase);
    GLD16(Vg0, VsB + wbase);
    GLD16(Vg1, VsB + 4096 + wbase);

    int jmax = 2 * qt + 1;
    for (int j = 0; j <= jmax; j++) {
        __syncthreads();   // drains GLD(j) (vmcnt0) + all waves done reading other buf
        if (j < jmax) {    // prefetch tile j+1 into the other buffer; latency hides
            int bo = ((j + 1) & 1) * 8192;
            GLD16(Kg0 + (size_t)(j + 1) * 64 * CC, KsB + bo + wbase);
            GLD16(Kg1 + (size_t)(j + 1) * 64 * CC, KsB + bo + 4096 + wbase);
            GLD16(Vg0 + (j + 1) * 64, VsB + bo + wbase);
            GLD16(Vg1 + (j + 1) * 64, VsB + bo + 4096 + wbase);
        }
        const __bf16* Kc = &Ks[j & 1][0];
        const __bf16* Vc = &Vs[j & 1][0];

        bool do0 = (j != jmax);          // strip 0 fully masked on the last k-tile

        // S^T = K.Q^T (pre-scaled): A = K rows (m=s), B = Q (n=q)
        f32x4 s2[2][4];
#pragma unroll
        for (int st = 0; st < 4; st++) {
            bf16x8 k0f = *(const bf16x8*)(Kc + (st * 16 + l15) * 64 + ((q8 ^ x7) * 8));
            bf16x8 k1f = *(const bf16x8*)(Kc + (st * 16 + l15) * 64 + (((q8 + 4) ^ x7) * 8));
            if (do0) {
                f32x4 t = zero;
                t = MFMA16(k0f, qfr[0][0], t);
                t = MFMA16(k1f, qfr[0][1], t);
                s2[0][st] = t;
            }
            f32x4 t = zero;
            t = MFMA16(k0f, qfr[1][0], t);
            t = MFMA16(k1f, qfr[1][1], t);
            s2[1][st] = t;
        }

        // softmax + P write + acc rescale, per strip
        bf16x8 bp[2][2];
#pragma unroll
        for (int qf = 0; qf < 2; qf++) {
            if (qf == 0 && !do0) continue;
            bool diag = (j == 2 * qt + qf);
            float mx = -1e30f;
#pragma unroll
            for (int st = 0; st < 4; st++) {
                f32x4 t = s2[qf][st];
                if (diag) {
                    int sb = st * 16 + q8 * 4;
                    if (sb + 0 > ql) t.x = -1e30f;
                    if (sb + 1 > ql) t.y = -1e30f;
                    if (sb + 2 > ql) t.z = -1e30f;
                    if (sb + 3 > ql) t.w = -1e30f;
                }
                s2[qf][st] = t;
                mx = fmaxf(mx, fmaxf(fmaxf(t.x, t.y), fmaxf(t.z, t.w)));
            }
            mx = fmaxf(mx, __shfl_xor(mx, 16));
            mx = fmaxf(mx, __shfl_xor(mx, 32));
            float mnew = fmaxf(m_i[qf], mx);
            float alpha = __builtin_amdgcn_exp2f(m_i[qf] - mnew);
            m_i[qf] = mnew;
#pragma unroll
            for (int st = 0; st < 4; st++) {
                bf16x4 pk;
                pk[0] = (__bf16)__builtin_amdgcn_exp2f(s2[qf][st].x - mnew);
                pk[1] = (__bf16)__builtin_amdgcn_exp2f(s2[qf][st].y - mnew);
                pk[2] = (__bf16)__builtin_amdgcn_exp2f(s2[qf][st].z - mnew);
                pk[3] = (__bf16)__builtin_amdgcn_exp2f(s2[qf][st].w - mnew);
                int swzc = (st * 2 + (q8 >> 1)) ^ x7;
                *(bf16x4*)(Ps[w] + l15 * 64 + swzc * 8 + (q8 & 1) * 4) = pk;
            }
#pragma unroll
            for (int t5 = 0; t5 < 5; t5++) acc[qf][t5] = acc[qf][t5] * alpha;
            // read this strip's P B-frags before the other strip overwrites Ps[w]
            bp[qf][0] = *(const bf16x8*)(Ps[w] + l15 * 64 + ((q8 ^ x7) * 8));
            bp[qf][1] = *(const bf16x8*)(Ps[w] + l15 * 64 + (((q8 + 4) ^ x7) * 8));
        }

        // O^T += V^T P^T  (A = V^T rows m=d, B = P^T n=q)
#pragma unroll
        for (int dt = 0; dt < 4; dt++) {
            bf16x8 v0 = *(const bf16x8*)(Vc + (dt * 16 + l15) * 64 + ((q8 ^ x7) * 8));
            bf16x8 v1 = *(const bf16x8*)(Vc + (dt * 16 + l15) * 64 + (((q8 + 4) ^ x7) * 8));
            if (do0) {
                acc[0][dt] = MFMA16(v0, bp[0][0], acc[0][dt]);
                acc[0][dt] = MFMA16(v1, bp[0][1], acc[0][dt]);
            }
            acc[1][dt] = MFMA16(v0, bp[1][0], acc[1][dt]);
            acc[1][dt] = MFMA16(v1, bp[1][1], acc[1][dt]);
        }
        if (do0) {
            acc[0][4] = MFMA16(ones, bp[0][0], acc[0][4]);
            acc[0][4] = MFMA16(ones, bp[0][1], acc[0][4]);
        }
        acc[1][4] = MFMA16(ones, bp[1][0], acc[1][4]);
        acc[1][4] = MFMA16(ones, bp[1][1], acc[1][4]);
    }

    // epilogue: O^T C-layout col=l15=q, row=q8*4+r=d; l sits in acc[*][4].x at lane l15
#pragma unroll
    for (int qf = 0; qf < 2; qf++) {
        float lsum = __shfl(acc[qf][4].x, l15);
        float ri = 1.0f / lsum;
        int q = qt * 128 + qf * 64 + w * 16 + l15;
        __bf16* yp = Y + (rowb + q) * CC + h * DH + q8 * 4;
#pragma unroll
        for (int dt = 0; dt < 4; dt++) {
            bf16x4 o;
            o[0] = (__bf16)(acc[qf][dt].x * ri);
            o[1] = (__bf16)(acc[qf][dt].y * ri);
            o[2] = (__bf16)(acc[qf][dt].z * ri);
            o[3] = (__bf16)(acc[qf][dt].w * ri);
            *(bf16x4*)(yp + dt * 16) = o;
        }
    }
}

// ---------- launch ----------
extern "C" void kernel_launch(void* const* d_in, const int* in_sizes, int n_in,
                              void* d_out, int out_size, void* d_ws, size_t ws_size,
                              hipStream_t stream) {
    const float* x  = (const float*)d_in[0];
    const float* wq = (const float*)d_in[1];
    const float* wk = (const float*)d_in[2];
    const float* wv = (const float*)d_in[3];
    const float* wo = (const float*)d_in[4];
    float* out = (float*)d_out;

    char* ws = (char*)d_ws;
    __bf16* xb  = (__bf16*)ws;                              // [0,16M): xb, then VT after QKV GEMM
    __bf16* wb  = (__bf16*)(ws + (size_t)16777216);         // [16M,24M): 4 weights bf16
    __bf16* qkv = (__bf16*)(ws + (size_t)25165824);         // [24M,72M): Q,K,V planes
    __bf16* yb  = (__bf16*)(ws + (size_t)75497472);         // [72M,88M): attn out bf16

    cvt_kernel<<<dim3(GM * GK / 8 / 256), 256, 0, stream>>>(x, xb, GM * GK / 8);
    cvt4_kernel<<<dim3(CC * CC / 8 / 256, 1, 4), 256, 0, stream>>>(wq, wk, wv, wo, wb);
    gemm_nt<<<dim3(GN / 128, GM / 128, 3), 256, 0, stream>>>(
        xb, wb, qkv, nullptr, (size_t)CC * CC, (size_t)GM * GN);
    // V plane -> VT [1024][8192]; xb region is dead now, reuse it
    transpose_kernel<<<dim3(GM / 64, GN / 64), 256, 0, stream>>>(
        qkv + (size_t)2 * GM * GN, xb);
    attn_kernel<<<dim3(16, BB * HH), 256, 0, stream>>>(
        qkv, qkv + (size_t)GM * GN, xb, yb);
    gemm_nt<<<dim3(GN / 128, GM / 128, 1), 256, 0, stream>>>(
        yb, wb + (size_t)3 * CC * CC, nullptr, out, 0, 0);
}

// Round 4
// 305.380 us; speedup vs baseline: 1.5374x; 1.2180x over previous
//
#include <hip/hip_runtime.h>
#include <hip/hip_bf16.h>
#include <stdint.h>

// ---------- types ----------
typedef __attribute__((ext_vector_type(8))) __bf16 bf16x8;
typedef __attribute__((ext_vector_type(4))) __bf16 bf16x4;
typedef __attribute__((ext_vector_type(4))) float  f32x4;

#define MFMA16(a, b, c) __builtin_amdgcn_mfma_f32_16x16x32_bf16((a), (b), (c), 0, 0, 0)

// async global->LDS, 16B per lane; LDS dest = wave-uniform base + lane*16
#define GLD16(gp, lp) __builtin_amdgcn_global_load_lds(                                   \
    (const __attribute__((address_space(1))) uint32_t*)(gp),                              \
    (__attribute__((address_space(3))) uint32_t*)(lp), 16, 0, 0)

// Problem constants
#define BB 4
#define TT 2048
#define CC 1024
#define HH 16
#define DH 64
#define GM 8192   // B*T
#define GN 1024
#define GK 1024

// ---------- fp32 -> bf16 conversion ----------
__global__ __launch_bounds__(256) void cvt_kernel(const float* __restrict__ src,
                                                  __bf16* __restrict__ dst, int n8) {
    int i = blockIdx.x * blockDim.x + threadIdx.x;
    if (i >= n8) return;
    const float4* s = (const float4*)src + (size_t)i * 2;
    float4 f0 = s[0], f1 = s[1];
    bf16x8 h;
    h[0] = (__bf16)f0.x; h[1] = (__bf16)f0.y; h[2] = (__bf16)f0.z; h[3] = (__bf16)f0.w;
    h[4] = (__bf16)f1.x; h[5] = (__bf16)f1.y; h[6] = (__bf16)f1.z; h[7] = (__bf16)f1.w;
    *(bf16x8*)(dst + (size_t)i * 8) = h;
}

__global__ __launch_bounds__(256) void cvt4_kernel(const float* __restrict__ w0,
                                                   const float* __restrict__ w1,
                                                   const float* __restrict__ w2,
                                                   const float* __restrict__ w3,
                                                   __bf16* __restrict__ dst) {
    const float* srcs[4] = {w0, w1, w2, w3};
    const float* src = srcs[blockIdx.z];
    __bf16* d = dst + (size_t)blockIdx.z * CC * CC;
    int i = blockIdx.x * blockDim.x + threadIdx.x;
    const float4* s = (const float4*)src + (size_t)i * 2;
    float4 f0 = s[0], f1 = s[1];
    bf16x8 h;
    h[0] = (__bf16)f0.x; h[1] = (__bf16)f0.y; h[2] = (__bf16)f0.z; h[3] = (__bf16)f0.w;
    h[4] = (__bf16)f1.x; h[5] = (__bf16)f1.y; h[6] = (__bf16)f1.z; h[7] = (__bf16)f1.w;
    *(bf16x8*)(d + (size_t)i * 8) = h;
}

// ---------- bf16 transpose: V [8192][1024] -> VT [1024][8192] ----------
__global__ __launch_bounds__(256) void transpose_kernel(const __bf16* __restrict__ V,
                                                        __bf16* __restrict__ VT) {
    __shared__ __bf16 Ts[64][72];  // +8 pad
    int tid = threadIdx.x;
    int m0 = blockIdx.x * 64, c0 = blockIdx.y * 64;
#pragma unroll
    for (int r = 0; r < 2; r++) {
        int ch = r * 256 + tid;
        int mm = ch >> 3, c8 = (ch & 7) * 8;
        *(uint4*)&Ts[mm][c8] = *(const uint4*)(V + (size_t)(m0 + mm) * CC + c0 + c8);
    }
    __syncthreads();
#pragma unroll
    for (int r = 0; r < 2; r++) {
        int ch = r * 256 + tid;
        int cc = ch >> 3, m8 = (ch & 7) * 8;
        bf16x8 v;
#pragma unroll
        for (int e = 0; e < 8; e++) v[e] = Ts[m8 + e][cc];
        *(bf16x8*)(VT + (size_t)(c0 + cc) * GM + m0 + m8) = v;
    }
}

// ---------- NT GEMM: C[m,n] = sum_k A[m,k] * B[n,k] ----------
// 128x128 tile, BK=32, global_load_lds width-16 staging (m97 structure).
__global__ __launch_bounds__(256) void gemm_nt(const __bf16* __restrict__ A,
                                               const __bf16* __restrict__ Bmat,
                                               __bf16* __restrict__ Cbf,
                                               float* __restrict__ Cf,
                                               size_t b_zstride, size_t c_zstride) {
    const __bf16* Bp = Bmat + (size_t)blockIdx.z * b_zstride;
    __shared__ __bf16 As[128 * 32];
    __shared__ __bf16 Bs[128 * 32];
    int tid  = threadIdx.x;
    int lane = tid & 63, w = tid >> 6;
    int wm = w >> 1, wn = w & 1;
    int l15 = lane & 15, q8 = lane >> 4;
    int m0 = blockIdx.y * 128, n0 = blockIdx.x * 128;

    f32x4 zero = {0.f, 0.f, 0.f, 0.f};
    f32x4 acc[4][4];
#pragma unroll
    for (int i = 0; i < 4; i++)
#pragma unroll
        for (int j = 0; j < 4; j++) acc[i][j] = zero;

    // staging chunk c -> LDS byte c*16 == (row c>>2, kcol (c&3)*8); lane-ordered.
    int c0 = tid, c1 = tid + 256;
    const __bf16* Ag0 = A  + (size_t)(m0 + (c0 >> 2)) * GK + (c0 & 3) * 8;
    const __bf16* Ag1 = A  + (size_t)(m0 + (c1 >> 2)) * GK + (c1 & 3) * 8;
    const __bf16* Bg0 = Bp + (size_t)(n0 + (c0 >> 2)) * GK + (c0 & 3) * 8;
    const __bf16* Bg1 = Bp + (size_t)(n0 + (c1 >> 2)) * GK + (c1 & 3) * 8;
    char* AsB = (char*)As; char* BsB = (char*)Bs;
    int wbase = (tid & ~63) * 16;   // wave-uniform chunk base (bytes)

    for (int k0 = 0; k0 < GK; k0 += 32) {
        __syncthreads();                 // prev iter's LDS reads done
        GLD16(Ag0 + k0, AsB + wbase);
        GLD16(Ag1 + k0, AsB + 4096 + wbase);
        GLD16(Bg0 + k0, BsB + wbase);
        GLD16(Bg1 + k0, BsB + 4096 + wbase);
        __syncthreads();                 // vmcnt drained before barrier -> staged
        bf16x8 af[4], bf[4];
#pragma unroll
        for (int mt = 0; mt < 4; mt++)
            af[mt] = *(const bf16x8*)(As + (wm * 64 + mt * 16 + l15) * 32 + q8 * 8);
#pragma unroll
        for (int nt = 0; nt < 4; nt++)
            bf[nt] = *(const bf16x8*)(Bs + (wn * 64 + nt * 16 + l15) * 32 + q8 * 8);
#pragma unroll
        for (int mt = 0; mt < 4; mt++)
#pragma unroll
            for (int nt = 0; nt < 4; nt++)
                acc[mt][nt] = MFMA16(af[mt], bf[nt], acc[mt][nt]);
    }

    // epilogue: C/D layout col = lane&15 (n), row = quad*4 + reg (m)
#pragma unroll
    for (int mt = 0; mt < 4; mt++) {
        int mrow = m0 + wm * 64 + mt * 16 + q8 * 4;
#pragma unroll
        for (int nt = 0; nt < 4; nt++) {
            int ncol = n0 + wn * 64 + nt * 16 + l15;
            f32x4 v = acc[mt][nt];
            if (Cf) {
                float* p = Cf + (size_t)blockIdx.z * c_zstride + (size_t)mrow * GN + ncol;
                p[0] = v.x; p[GN] = v.y; p[2 * GN] = v.z; p[3 * GN] = v.w;
            } else {
                __bf16* p = Cbf + (size_t)blockIdx.z * c_zstride + (size_t)mrow * GN + ncol;
                p[0] = (__bf16)v.x; p[GN] = (__bf16)v.y;
                p[2 * GN] = (__bf16)v.z; p[3 * GN] = (__bf16)v.w;
            }
        }
    }
}

// ---------- flash attention, causal, S^T formulation, double-buffered ----------
// Block: 128 q-rows (2 strips of 64), K-tile 64, K/V LDS double-buffered.
// Grid (bh=64, y=16) with a y->qt permutation chosen so the 4 blocks co-resident
// on a CU (ids congruent mod 256 under round-robin dispatch) have qt summing to
// 30 -> every CU gets exactly 68 k-iters (was: same-qt grouping, 128-iter tail
// on 16 CUs of XCD0 -> Occupancy 10.9%). Both strips' softmax chains interleaved;
// masking branch-free (strip0's one dead iter runs fully-masked: P=0, alpha=1).
__global__ __launch_bounds__(256) void attn_kernel(const __bf16* __restrict__ Q,
                                                   const __bf16* __restrict__ K,
                                                   const __bf16* __restrict__ VT,
                                                   __bf16* __restrict__ Y) {
    __shared__ __bf16 Ks[2][64 * 64];  // [s][d], chunk-swizzled, dbuf
    __shared__ __bf16 Vs[2][64 * 64];  // [d][s], chunk-swizzled, dbuf
    __shared__ __bf16 Ps[4][16 * 64];  // per-wave P [q][s], chunk-swizzled

    int tid  = threadIdx.x;
    int lane = tid & 63, w = tid >> 6;
    int l15 = lane & 15, q8 = lane >> 4;
    // balanced qt permutation: y0=y&3 selects the CU group, k=y>>2 the member
    int y  = blockIdx.y, y0 = y & 3, kk = y >> 2;
    int qt = (kk & 1) ? (2 * y0 + (kk >> 1)) : (15 - (kk >> 1) - 2 * y0);
    int bh = blockIdx.x, b = bh >> 4, h = bh & 15;
    size_t rowb = (size_t)b * TT;
    const float SC = 0.125f * 1.44269504f;   // scale * log2(e), folded into Q
    int ql = w * 16 + l15;             // q offset within strip
    int x7 = l15 & 7;                  // xor-swizzle key (row & 7)

    // Q B-frags (n = q, k = d), pre-scaled by SC (once per block, not per iter)
    bf16x8 qfr[2][2];
#pragma unroll
    for (int qf = 0; qf < 2; qf++) {
        int q = qt * 128 + qf * 64 + w * 16 + l15;
        const __bf16* qp = Q + (rowb + q) * CC + h * DH + q8 * 8;
        bf16x8 r0 = *(const bf16x8*)qp;
        bf16x8 r1 = *(const bf16x8*)(qp + 32);
#pragma unroll
        for (int e = 0; e < 8; e++) {
            r0[e] = (__bf16)((float)r0[e] * SC);
            r1[e] = (__bf16)((float)r1[e] * SC);
        }
        qfr[qf][0] = r0; qfr[qf][1] = r1;
    }

    f32x4 zero = {0.f, 0.f, 0.f, 0.f};
    f32x4 acc[2][5];
    float m_i[2] = {-1e30f, -1e30f};
#pragma unroll
    for (int qf = 0; qf < 2; qf++)
#pragma unroll
        for (int t5 = 0; t5 < 5; t5++) acc[qf][t5] = zero;

    // ones A-frag: row 0 of dt=4 tile accumulates l = sum_s P^T[s][q]
    bf16x8 ones;
#pragma unroll
    for (int e = 0; e < 8; e++) ones[e] = (l15 == 0) ? (__bf16)1.0f : (__bf16)0.0f;

    // staging: chunk c -> (row c>>3, swizzled col-chunk c&7)
    int c0 = tid, c1 = tid + 256;
    int s0 = c0 >> 3, d80 = ((c0 & 7) ^ (s0 & 7)) * 8;
    int s1 = c1 >> 3, d81 = ((c1 & 7) ^ (s1 & 7)) * 8;
    const __bf16* Kg0 = K + (rowb + s0) * CC + h * DH + d80;
    const __bf16* Kg1 = K + (rowb + s1) * CC + h * DH + d81;
    const __bf16* Vg0 = VT + (size_t)(h * DH + s0) * GM + rowb + d80;
    const __bf16* Vg1 = VT + (size_t)(h * DH + s1) * GM + rowb + d81;
    char* KsB = (char*)Ks; char* VsB = (char*)Vs;
    int wbase = (tid & ~63) * 16;

    // prologue: stage tile 0 into buffer 0
    GLD16(Kg0, KsB + wbase);
    GLD16(Kg1, KsB + 4096 + wbase);
    GLD16(Vg0, VsB + wbase);
    GLD16(Vg1, VsB + 4096 + wbase);

    int jmax = 2 * qt + 1;
    for (int j = 0; j <= jmax; j++) {
        __syncthreads();   // drains GLD(j) (vmcnt0) + all waves done reading other buf
        if (j < jmax) {    // prefetch tile j+1 into the other buffer; latency hides
            int bo = ((j + 1) & 1) * 8192;
            GLD16(Kg0 + (size_t)(j + 1) * 64 * CC, KsB + bo + wbase);
            GLD16(Kg1 + (size_t)(j + 1) * 64 * CC, KsB + bo + 4096 + wbase);
            GLD16(Vg0 + (j + 1) * 64, VsB + bo + wbase);
            GLD16(Vg1 + (j + 1) * 64, VsB + bo + 4096 + wbase);
        }
        const __bf16* Kc = &Ks[j & 1][0];
        const __bf16* Vc = &Vs[j & 1][0];

        // phase A: S^T = K.Q^T (pre-scaled), both strips
        f32x4 s2[2][4];
#pragma unroll
        for (int st = 0; st < 4; st++) {
            bf16x8 k0f = *(const bf16x8*)(Kc + (st * 16 + l15) * 64 + ((q8 ^ x7) * 8));
            bf16x8 k1f = *(const bf16x8*)(Kc + (st * 16 + l15) * 64 + (((q8 + 4) ^ x7) * 8));
            f32x4 t0 = zero, t1 = zero;
            t0 = MFMA16(k0f, qfr[0][0], t0);
            t0 = MFMA16(k1f, qfr[0][1], t0);
            t1 = MFMA16(k0f, qfr[1][0], t1);
            t1 = MFMA16(k1f, qfr[1][1], t1);
            s2[0][st] = t0; s2[1][st] = t1;
        }

        // phase B: branch-free causal mask + row max, both strips
        // thr = 63 (no mask) before the diagonal; = ql on it; < 0 past it
        float mx[2];
#pragma unroll
        for (int qf = 0; qf < 2; qf++) {
            int thr = min(63, ql - (j - 2 * qt - qf) * 64);
            float m = -1e30f;
#pragma unroll
            for (int st = 0; st < 4; st++) {
                f32x4 t = s2[qf][st];
                int sb = st * 16 + q8 * 4;
                t.x = (sb + 0 > thr) ? -1e30f : t.x;
                t.y = (sb + 1 > thr) ? -1e30f : t.y;
                t.z = (sb + 2 > thr) ? -1e30f : t.z;
                t.w = (sb + 3 > thr) ? -1e30f : t.w;
                s2[qf][st] = t;
                m = fmaxf(m, fmaxf(fmaxf(t.x, t.y), fmaxf(t.z, t.w)));
            }
            mx[qf] = m;
        }

        // phase C: cross-lane max, chains interleaved
        mx[0] = fmaxf(mx[0], __shfl_xor(mx[0], 16));
        mx[1] = fmaxf(mx[1], __shfl_xor(mx[1], 16));
        mx[0] = fmaxf(mx[0], __shfl_xor(mx[0], 32));
        mx[1] = fmaxf(mx[1], __shfl_xor(mx[1], 32));

        // phase D: online-softmax scalars + exp, both strips
        float alpha[2];
        bf16x4 pk[2][4];
#pragma unroll
        for (int qf = 0; qf < 2; qf++) {
            float mnew = fmaxf(m_i[qf], mx[qf]);
            alpha[qf] = __builtin_amdgcn_exp2f(m_i[qf] - mnew);
            m_i[qf] = mnew;
#pragma unroll
            for (int st = 0; st < 4; st++) {
                pk[qf][st][0] = (__bf16)__builtin_amdgcn_exp2f(s2[qf][st].x - mnew);
                pk[qf][st][1] = (__bf16)__builtin_amdgcn_exp2f(s2[qf][st].y - mnew);
                pk[qf][st][2] = (__bf16)__builtin_amdgcn_exp2f(s2[qf][st].z - mnew);
                pk[qf][st][3] = (__bf16)__builtin_amdgcn_exp2f(s2[qf][st].w - mnew);
            }
        }

        // phase E: P round-trip through per-wave LDS (in-order per-wave DS ops
        // make write1-after-read0 safe without a barrier)
        bf16x8 bp[2][2];
#pragma unroll
        for (int st = 0; st < 4; st++) {
            int swzc = (st * 2 + (q8 >> 1)) ^ x7;
            *(bf16x4*)(Ps[w] + l15 * 64 + swzc * 8 + (q8 & 1) * 4) = pk[0][st];
        }
        bp[0][0] = *(const bf16x8*)(Ps[w] + l15 * 64 + ((q8 ^ x7) * 8));
        bp[0][1] = *(const bf16x8*)(Ps[w] + l15 * 64 + (((q8 + 4) ^ x7) * 8));
#pragma unroll
        for (int st = 0; st < 4; st++) {
            int swzc = (st * 2 + (q8 >> 1)) ^ x7;
            *(bf16x4*)(Ps[w] + l15 * 64 + swzc * 8 + (q8 & 1) * 4) = pk[1][st];
        }
        bp[1][0] = *(const bf16x8*)(Ps[w] + l15 * 64 + ((q8 ^ x7) * 8));
        bp[1][1] = *(const bf16x8*)(Ps[w] + l15 * 64 + (((q8 + 4) ^ x7) * 8));

        // phase F: rescale accumulators (VALU overlaps phase-E lgkm waits)
#pragma unroll
        for (int qf = 0; qf < 2; qf++)
#pragma unroll
            for (int t5 = 0; t5 < 5; t5++) acc[qf][t5] = acc[qf][t5] * alpha[qf];

        // phase G: O^T += V^T P^T, both strips
#pragma unroll
        for (int dt = 0; dt < 4; dt++) {
            bf16x8 v0 = *(const bf16x8*)(Vc + (dt * 16 + l15) * 64 + ((q8 ^ x7) * 8));
            bf16x8 v1 = *(const bf16x8*)(Vc + (dt * 16 + l15) * 64 + (((q8 + 4) ^ x7) * 8));
            acc[0][dt] = MFMA16(v0, bp[0][0], acc[0][dt]);
            acc[0][dt] = MFMA16(v1, bp[0][1], acc[0][dt]);
            acc[1][dt] = MFMA16(v0, bp[1][0], acc[1][dt]);
            acc[1][dt] = MFMA16(v1, bp[1][1], acc[1][dt]);
        }
        acc[0][4] = MFMA16(ones, bp[0][0], acc[0][4]);
        acc[0][4] = MFMA16(ones, bp[0][1], acc[0][4]);
        acc[1][4] = MFMA16(ones, bp[1][0], acc[1][4]);
        acc[1][4] = MFMA16(ones, bp[1][1], acc[1][4]);
    }

    // epilogue: O^T C-layout col=l15=q, row=q8*4+r=d; l sits in acc[*][4].x at lane l15
#pragma unroll
    for (int qf = 0; qf < 2; qf++) {
        float lsum = __shfl(acc[qf][4].x, l15);
        float ri = 1.0f / lsum;
        int q = qt * 128 + qf * 64 + w * 16 + l15;
        __bf16* yp = Y + (rowb + q) * CC + h * DH + q8 * 4;
#pragma unroll
        for (int dt = 0; dt < 4; dt++) {
            bf16x4 o;
            o[0] = (__bf16)(acc[qf][dt].x * ri);
            o[1] = (__bf16)(acc[qf][dt].y * ri);
            o[2] = (__bf16)(acc[qf][dt].z * ri);
            o[3] = (__bf16)(acc[qf][dt].w * ri);
            *(bf16x4*)(yp + dt * 16) = o;
        }
    }
}

// ---------- launch ----------
extern "C" void kernel_launch(void* const* d_in, const int* in_sizes, int n_in,
                              void* d_out, int out_size, void* d_ws, size_t ws_size,
                              hipStream_t stream) {
    const float* x  = (const float*)d_in[0];
    const float* wq = (const float*)d_in[1];
    const float* wk = (const float*)d_in[2];
    const float* wv = (const float*)d_in[3];
    const float* wo = (const float*)d_in[4];
    float* out = (float*)d_out;

    char* ws = (char*)d_ws;
    __bf16* xb  = (__bf16*)ws;                              // [0,16M): xb, then VT after QKV GEMM
    __bf16* wb  = (__bf16*)(ws + (size_t)16777216);         // [16M,24M): 4 weights bf16
    __bf16* qkv = (__bf16*)(ws + (size_t)25165824);         // [24M,72M): Q,K,V planes
    __bf16* yb  = (__bf16*)(ws + (size_t)75497472);         // [72M,88M): attn out bf16

    cvt_kernel<<<dim3(GM * GK / 8 / 256), 256, 0, stream>>>(x, xb, GM * GK / 8);
    cvt4_kernel<<<dim3(CC * CC / 8 / 256, 1, 4), 256, 0, stream>>>(wq, wk, wv, wo, wb);
    gemm_nt<<<dim3(GN / 128, GM / 128, 3), 256, 0, stream>>>(
        xb, wb, qkv, nullptr, (size_t)CC * CC, (size_t)GM * GN);
    // V plane -> VT [1024][8192]; xb region is dead now, reuse it
    transpose_kernel<<<dim3(GM / 64, GN / 64), 256, 0, stream>>>(
        qkv + (size_t)2 * GM * GN, xb);
    // grid: x = bh (64), y = balanced qt permutation (16)
    attn_kernel<<<dim3(BB * HH, 16), 256, 0, stream>>>(
        qkv, qkv + (size_t)GM * GN, xb, yb);
    gemm_nt<<<dim3(GN / 128, GM / 128, 1), 256, 0, stream>>>(
        yb, wb + (size_t)3 * CC * CC, nullptr, out, 0, 0);
}

// Round 5
// 290.351 us; speedup vs baseline: 1.6170x; 1.0518x over previous
//
#include <hip/hip_runtime.h>
#include <hip/hip_bf16.h>
#include <stdint.h>

// ---------- types ----------
typedef __attribute__((ext_vector_type(8))) __bf16 bf16x8;
typedef __attribute__((ext_vector_type(4))) __bf16 bf16x4;
typedef __attribute__((ext_vector_type(4))) float  f32x4;

#define MFMA16(a, b, c) __builtin_amdgcn_mfma_f32_16x16x32_bf16((a), (b), (c), 0, 0, 0)

// async global->LDS, 16B per lane; LDS dest = wave-uniform base + lane*16
#define GLD16(gp, lp) __builtin_amdgcn_global_load_lds(                                   \
    (const __attribute__((address_space(1))) uint32_t*)(gp),                              \
    (__attribute__((address_space(3))) uint32_t*)(lp), 16, 0, 0)

// Problem constants
#define BB 4
#define TT 2048
#define CC 1024
#define HH 16
#define DH 64
#define GM 8192   // B*T
#define GN 1024
#define GK 1024

// ---------- fp32 -> bf16 conversion ----------
__global__ __launch_bounds__(256) void cvt_kernel(const float* __restrict__ src,
                                                  __bf16* __restrict__ dst, int n8) {
    int i = blockIdx.x * blockDim.x + threadIdx.x;
    if (i >= n8) return;
    const float4* s = (const float4*)src + (size_t)i * 2;
    float4 f0 = s[0], f1 = s[1];
    bf16x8 h;
    h[0] = (__bf16)f0.x; h[1] = (__bf16)f0.y; h[2] = (__bf16)f0.z; h[3] = (__bf16)f0.w;
    h[4] = (__bf16)f1.x; h[5] = (__bf16)f1.y; h[6] = (__bf16)f1.z; h[7] = (__bf16)f1.w;
    *(bf16x8*)(dst + (size_t)i * 8) = h;
}

__global__ __launch_bounds__(256) void cvt4_kernel(const float* __restrict__ w0,
                                                   const float* __restrict__ w1,
                                                   const float* __restrict__ w2,
                                                   const float* __restrict__ w3,
                                                   __bf16* __restrict__ dst) {
    const float* srcs[4] = {w0, w1, w2, w3};
    const float* src = srcs[blockIdx.z];
    __bf16* d = dst + (size_t)blockIdx.z * CC * CC;
    int i = blockIdx.x * blockDim.x + threadIdx.x;
    const float4* s = (const float4*)src + (size_t)i * 2;
    float4 f0 = s[0], f1 = s[1];
    bf16x8 h;
    h[0] = (__bf16)f0.x; h[1] = (__bf16)f0.y; h[2] = (__bf16)f0.z; h[3] = (__bf16)f0.w;
    h[4] = (__bf16)f1.x; h[5] = (__bf16)f1.y; h[6] = (__bf16)f1.z; h[7] = (__bf16)f1.w;
    *(bf16x8*)(d + (size_t)i * 8) = h;
}

// ---------- bf16 transpose: V [8192][1024] -> VT [1024][8192] ----------
__global__ __launch_bounds__(256) void transpose_kernel(const __bf16* __restrict__ V,
                                                        __bf16* __restrict__ VT) {
    __shared__ __bf16 Ts[64][72];  // +8 pad
    int tid = threadIdx.x;
    int m0 = blockIdx.x * 64, c0 = blockIdx.y * 64;
#pragma unroll
    for (int r = 0; r < 2; r++) {
        int ch = r * 256 + tid;
        int mm = ch >> 3, c8 = (ch & 7) * 8;
        *(uint4*)&Ts[mm][c8] = *(const uint4*)(V + (size_t)(m0 + mm) * CC + c0 + c8);
    }
    __syncthreads();
#pragma unroll
    for (int r = 0; r < 2; r++) {
        int ch = r * 256 + tid;
        int cc = ch >> 3, m8 = (ch & 7) * 8;
        bf16x8 v;
#pragma unroll
        for (int e = 0; e < 8; e++) v[e] = Ts[m8 + e][cc];
        *(bf16x8*)(VT + (size_t)(c0 + cc) * GM + m0 + m8) = v;
    }
}

// ---------- NT GEMM: C[m,n] = sum_k A[m,k] * B[n,k] ----------
// 128x128 tile, BK=64 (two 32-wide k-halves per barrier pair -> 32 MFMA/barrier,
// halves barrier count vs BK=32). LDS 32 KB -> 5 blocks/CU. LDS layout per
// matrix: [half][128][32]; GLD16 chunk c (lds bytes c*16) <- global
// (row=(c&511)>>2, k = (c>>9)*32 + (c&3)*8) — frag reads identical to BK=32.
__global__ __launch_bounds__(256) void gemm_nt(const __bf16* __restrict__ A,
                                               const __bf16* __restrict__ Bmat,
                                               __bf16* __restrict__ Cbf,
                                               float* __restrict__ Cf,
                                               size_t b_zstride, size_t c_zstride) {
    const __bf16* Bp = Bmat + (size_t)blockIdx.z * b_zstride;
    __shared__ __bf16 As[2 * 128 * 32];
    __shared__ __bf16 Bs[2 * 128 * 32];
    int tid  = threadIdx.x;
    int lane = tid & 63, w = tid >> 6;
    int wm = w >> 1, wn = w & 1;
    int l15 = lane & 15, q8 = lane >> 4;
    int m0 = blockIdx.y * 128, n0 = blockIdx.x * 128;

    f32x4 zero = {0.f, 0.f, 0.f, 0.f};
    f32x4 acc[4][4];
#pragma unroll
    for (int i = 0; i < 4; i++)
#pragma unroll
        for (int j = 0; j < 4; j++) acc[i][j] = zero;

    const __bf16* Ag[4];
    const __bf16* Bg[4];
#pragma unroll
    for (int t = 0; t < 4; t++) {
        int c = tid + 256 * t;
        int half = c >> 9, row = (c & 511) >> 2, kc = (c & 3) * 8;
        Ag[t] = A  + (size_t)(m0 + row) * GK + half * 32 + kc;
        Bg[t] = Bp + (size_t)(n0 + row) * GK + half * 32 + kc;
    }
    char* AsB = (char*)As; char* BsB = (char*)Bs;
    int wbase = (tid & ~63) * 16;   // wave-uniform chunk base (bytes)

    for (int k0 = 0; k0 < GK; k0 += 64) {
        __syncthreads();                 // prev iter's LDS reads done
#pragma unroll
        for (int t = 0; t < 4; t++) {
            GLD16(Ag[t] + k0, AsB + t * 4096 + wbase);
            GLD16(Bg[t] + k0, BsB + t * 4096 + wbase);
        }
        __syncthreads();                 // vmcnt drained before barrier -> staged
#pragma unroll
        for (int kk = 0; kk < 2; kk++) {
            bf16x8 af[4], bf[4];
#pragma unroll
            for (int mt = 0; mt < 4; mt++)
                af[mt] = *(const bf16x8*)(As + kk * 4096 + (wm * 64 + mt * 16 + l15) * 32 + q8 * 8);
#pragma unroll
            for (int nt = 0; nt < 4; nt++)
                bf[nt] = *(const bf16x8*)(Bs + kk * 4096 + (wn * 64 + nt * 16 + l15) * 32 + q8 * 8);
#pragma unroll
            for (int mt = 0; mt < 4; mt++)
#pragma unroll
                for (int nt = 0; nt < 4; nt++)
                    acc[mt][nt] = MFMA16(af[mt], bf[nt], acc[mt][nt]);
        }
    }

    // epilogue: C/D layout col = lane&15 (n), row = quad*4 + reg (m)
#pragma unroll
    for (int mt = 0; mt < 4; mt++) {
        int mrow = m0 + wm * 64 + mt * 16 + q8 * 4;
#pragma unroll
        for (int nt = 0; nt < 4; nt++) {
            int ncol = n0 + wn * 64 + nt * 16 + l15;
            f32x4 v = acc[mt][nt];
            if (Cf) {
                float* p = Cf + (size_t)blockIdx.z * c_zstride + (size_t)mrow * GN + ncol;
                p[0] = v.x; p[GN] = v.y; p[2 * GN] = v.z; p[3 * GN] = v.w;
            } else {
                __bf16* p = Cbf + (size_t)blockIdx.z * c_zstride + (size_t)mrow * GN + ncol;
                p[0] = (__bf16)v.x; p[GN] = (__bf16)v.y;
                p[2 * GN] = (__bf16)v.z; p[3 * GN] = (__bf16)v.w;
            }
        }
    }
}

// ---------- flash attention, causal, S^T formulation, fold-paired strips ----------
// Block y handles q-tiles {y, 31-y} (64 rows each). Strip B (tile 31-y) needs key
// tiles 0..31-y; strip A (tile y) is co-computed on the shared prefix j<=y.
// => EVERY block does exactly 33 strip-iters: no straggler blocks (R4's balanced-sum
// grouping still had per-CU tails since co-resident blocks run concurrently).
// Causal masking only on each strip's diagonal iter (wave-uniform branch).
__global__ __launch_bounds__(256) void attn_kernel(const __bf16* __restrict__ Q,
                                                   const __bf16* __restrict__ K,
                                                   const __bf16* __restrict__ VT,
                                                   __bf16* __restrict__ Y) {
    __shared__ __bf16 Ks[2][64 * 64];  // [s][d], chunk-swizzled, dbuf
    __shared__ __bf16 Vs[2][64 * 64];  // [d][s], chunk-swizzled, dbuf
    __shared__ __bf16 Ps[4][16 * 64];  // per-wave P [q][s], chunk-swizzled

    int tid  = threadIdx.x;
    int lane = tid & 63, w = tid >> 6;
    int l15 = lane & 15, q8 = lane >> 4;
    int y  = blockIdx.y;               // 0..15
    int tA = y, tB = 31 - y;           // paired q-tiles; work = (tA+1)+(tB+1) = 33
    int bh = blockIdx.x, b = bh >> 4, h = bh & 15;
    size_t rowb = (size_t)b * TT;
    const float SC = 0.125f * 1.44269504f;   // scale * log2(e), folded into Q
    int ql = w * 16 + l15;             // q offset within strip
    int x7 = l15 & 7;                  // xor-swizzle key (row & 7)

    // Q B-frags (n = q, k = d), pre-scaled by SC; strip 0 = tile tA, strip 1 = tile tB
    bf16x8 qfr[2][2];
#pragma unroll
    for (int qf = 0; qf < 2; qf++) {
        int tile = qf ? tB : tA;
        int q = tile * 64 + w * 16 + l15;
        const __bf16* qp = Q + (rowb + q) * CC + h * DH + q8 * 8;
        bf16x8 r0 = *(const bf16x8*)qp;
        bf16x8 r1 = *(const bf16x8*)(qp + 32);
#pragma unroll
        for (int e = 0; e < 8; e++) {
            r0[e] = (__bf16)((float)r0[e] * SC);
            r1[e] = (__bf16)((float)r1[e] * SC);
        }
        qfr[qf][0] = r0; qfr[qf][1] = r1;
    }

    f32x4 zero = {0.f, 0.f, 0.f, 0.f};
    f32x4 acc[2][5];
    float m_i[2] = {-1e30f, -1e30f};
#pragma unroll
    for (int qf = 0; qf < 2; qf++)
#pragma unroll
        for (int t5 = 0; t5 < 5; t5++) acc[qf][t5] = zero;

    // ones A-frag: row 0 of dt=4 tile accumulates l = sum_s P^T[s][q]
    bf16x8 ones;
#pragma unroll
    for (int e = 0; e < 8; e++) ones[e] = (l15 == 0) ? (__bf16)1.0f : (__bf16)0.0f;

    // staging: chunk c -> (row c>>3, swizzled col-chunk c&7)
    int c0 = tid, c1 = tid + 256;
    int s0 = c0 >> 3, d80 = ((c0 & 7) ^ (s0 & 7)) * 8;
    int s1 = c1 >> 3, d81 = ((c1 & 7) ^ (s1 & 7)) * 8;
    const __bf16* Kg0 = K + (rowb + s0) * CC + h * DH + d80;
    const __bf16* Kg1 = K + (rowb + s1) * CC + h * DH + d81;
    const __bf16* Vg0 = VT + (size_t)(h * DH + s0) * GM + rowb + d80;
    const __bf16* Vg1 = VT + (size_t)(h * DH + s1) * GM + rowb + d81;
    char* KsB = (char*)Ks; char* VsB = (char*)Vs;
    int wbase = (tid & ~63) * 16;

    // prologue: stage key-tile 0 into buffer 0
    GLD16(Kg0, KsB + wbase);
    GLD16(Kg1, KsB + 4096 + wbase);
    GLD16(Vg0, VsB + wbase);
    GLD16(Vg1, VsB + 4096 + wbase);

    int jmax = tB;
    for (int j = 0; j <= jmax; j++) {
        __syncthreads();   // drains GLD(j) (vmcnt0) + all waves done reading other buf
        if (j < jmax) {    // prefetch tile j+1 into the other buffer; latency hides
            int bo = ((j + 1) & 1) * 8192;
            GLD16(Kg0 + (size_t)(j + 1) * 64 * CC, KsB + bo + wbase);
            GLD16(Kg1 + (size_t)(j + 1) * 64 * CC, KsB + bo + 4096 + wbase);
            GLD16(Vg0 + (j + 1) * 64, VsB + bo + wbase);
            GLD16(Vg1 + (j + 1) * 64, VsB + bo + 4096 + wbase);
        }
        const __bf16* Kc = &Ks[j & 1][0];
        const __bf16* Vc = &Vs[j & 1][0];
        bool doA = (j <= tA);            // strip 0 active on the shared prefix

        // phase A: S^T = K.Q^T (pre-scaled)
        f32x4 s2[2][4];
#pragma unroll
        for (int st = 0; st < 4; st++) {
            bf16x8 k0f = *(const bf16x8*)(Kc + (st * 16 + l15) * 64 + ((q8 ^ x7) * 8));
            bf16x8 k1f = *(const bf16x8*)(Kc + (st * 16 + l15) * 64 + (((q8 + 4) ^ x7) * 8));
            f32x4 t1 = zero;
            t1 = MFMA16(k0f, qfr[1][0], t1);
            t1 = MFMA16(k1f, qfr[1][1], t1);
            s2[1][st] = t1;
            if (doA) {
                f32x4 t0 = zero;
                t0 = MFMA16(k0f, qfr[0][0], t0);
                t0 = MFMA16(k1f, qfr[0][1], t0);
                s2[0][st] = t0;
            }
        }

        // phase B: causal mask — diagonal iters only (wave-uniform branches)
        if (j == tA) {
#pragma unroll
            for (int st = 0; st < 4; st++) {
                f32x4 t = s2[0][st];
                int sb = st * 16 + q8 * 4;
                t.x = (sb + 0 > ql) ? -1e30f : t.x;
                t.y = (sb + 1 > ql) ? -1e30f : t.y;
                t.z = (sb + 2 > ql) ? -1e30f : t.z;
                t.w = (sb + 3 > ql) ? -1e30f : t.w;
                s2[0][st] = t;
            }
        }
        if (j == tB) {
#pragma unroll
            for (int st = 0; st < 4; st++) {
                f32x4 t = s2[1][st];
                int sb = st * 16 + q8 * 4;
                t.x = (sb + 0 > ql) ? -1e30f : t.x;
                t.y = (sb + 1 > ql) ? -1e30f : t.y;
                t.z = (sb + 2 > ql) ? -1e30f : t.z;
                t.w = (sb + 3 > ql) ? -1e30f : t.w;
                s2[1][st] = t;
            }
        }

        // phase C: row max (per-lane tree + 2 shuffles), chains interleaved
        float mx[2];
#pragma unroll
        for (int qf = 0; qf < 2; qf++) {
            if (qf == 0 && !doA) continue;
            float m = -1e30f;
#pragma unroll
            for (int st = 0; st < 4; st++) {
                f32x4 t = s2[qf][st];
                m = fmaxf(m, fmaxf(fmaxf(t.x, t.y), fmaxf(t.z, t.w)));
            }
            mx[qf] = m;
        }
        if (doA) {
            mx[0] = fmaxf(mx[0], __shfl_xor(mx[0], 16));
            mx[1] = fmaxf(mx[1], __shfl_xor(mx[1], 16));
            mx[0] = fmaxf(mx[0], __shfl_xor(mx[0], 32));
            mx[1] = fmaxf(mx[1], __shfl_xor(mx[1], 32));
        } else {
            mx[1] = fmaxf(mx[1], __shfl_xor(mx[1], 16));
            mx[1] = fmaxf(mx[1], __shfl_xor(mx[1], 32));
        }

        // phase D: online-softmax scalars + exp
        float alpha[2];
        bf16x4 pk[2][4];
#pragma unroll
        for (int qf = 0; qf < 2; qf++) {
            if (qf == 0 && !doA) continue;
            float mnew = fmaxf(m_i[qf], mx[qf]);
            alpha[qf] = __builtin_amdgcn_exp2f(m_i[qf] - mnew);
            m_i[qf] = mnew;
#pragma unroll
            for (int st = 0; st < 4; st++) {
                pk[qf][st][0] = (__bf16)__builtin_amdgcn_exp2f(s2[qf][st].x - mnew);
                pk[qf][st][1] = (__bf16)__builtin_amdgcn_exp2f(s2[qf][st].y - mnew);
                pk[qf][st][2] = (__bf16)__builtin_amdgcn_exp2f(s2[qf][st].z - mnew);
                pk[qf][st][3] = (__bf16)__builtin_amdgcn_exp2f(s2[qf][st].w - mnew);
            }
        }

        // phase E: P round-trip through per-wave LDS (per-wave DS ordering makes
        // write-after-read safe without barriers)
        bf16x8 bp[2][2];
#pragma unroll
        for (int qf = 0; qf < 2; qf++) {
            if (qf == 0 && !doA) continue;
#pragma unroll
            for (int st = 0; st < 4; st++) {
                int swzc = (st * 2 + (q8 >> 1)) ^ x7;
                *(bf16x4*)(Ps[w] + l15 * 64 + swzc * 8 + (q8 & 1) * 4) = pk[qf][st];
            }
            bp[qf][0] = *(const bf16x8*)(Ps[w] + l15 * 64 + ((q8 ^ x7) * 8));
            bp[qf][1] = *(const bf16x8*)(Ps[w] + l15 * 64 + (((q8 + 4) ^ x7) * 8));
        }

        // phase F: rescale accumulators
#pragma unroll
        for (int qf = 0; qf < 2; qf++) {
            if (qf == 0 && !doA) continue;
#pragma unroll
            for (int t5 = 0; t5 < 5; t5++) acc[qf][t5] = acc[qf][t5] * alpha[qf];
        }

        // phase G: O^T += V^T P^T
#pragma unroll
        for (int dt = 0; dt < 4; dt++) {
            bf16x8 v0 = *(const bf16x8*)(Vc + (dt * 16 + l15) * 64 + ((q8 ^ x7) * 8));
            bf16x8 v1 = *(const bf16x8*)(Vc + (dt * 16 + l15) * 64 + (((q8 + 4) ^ x7) * 8));
            acc[1][dt] = MFMA16(v0, bp[1][0], acc[1][dt]);
            acc[1][dt] = MFMA16(v1, bp[1][1], acc[1][dt]);
            if (doA) {
                acc[0][dt] = MFMA16(v0, bp[0][0], acc[0][dt]);
                acc[0][dt] = MFMA16(v1, bp[0][1], acc[0][dt]);
            }
        }
        acc[1][4] = MFMA16(ones, bp[1][0], acc[1][4]);
        acc[1][4] = MFMA16(ones, bp[1][1], acc[1][4]);
        if (doA) {
            acc[0][4] = MFMA16(ones, bp[0][0], acc[0][4]);
            acc[0][4] = MFMA16(ones, bp[0][1], acc[0][4]);
        }
    }

    // epilogue: O^T C-layout col=l15=q, row=q8*4+r=d; l sits in acc[*][4].x at lane l15
#pragma unroll
    for (int qf = 0; qf < 2; qf++) {
        float lsum = __shfl(acc[qf][4].x, l15);
        float ri = 1.0f / lsum;
        int tile = qf ? tB : tA;
        int q = tile * 64 + w * 16 + l15;
        __bf16* yp = Y + (rowb + q) * CC + h * DH + q8 * 4;
#pragma unroll
        for (int dt = 0; dt < 4; dt++) {
            bf16x4 o;
            o[0] = (__bf16)(acc[qf][dt].x * ri);
            o[1] = (__bf16)(acc[qf][dt].y * ri);
            o[2] = (__bf16)(acc[qf][dt].z * ri);
            o[3] = (__bf16)(acc[qf][dt].w * ri);
            *(bf16x4*)(yp + dt * 16) = o;
        }
    }
}

// ---------- launch ----------
extern "C" void kernel_launch(void* const* d_in, const int* in_sizes, int n_in,
                              void* d_out, int out_size, void* d_ws, size_t ws_size,
                              hipStream_t stream) {
    const float* x  = (const float*)d_in[0];
    const float* wq = (const float*)d_in[1];
    const float* wk = (const float*)d_in[2];
    const float* wv = (const float*)d_in[3];
    const float* wo = (const float*)d_in[4];
    float* out = (float*)d_out;

    char* ws = (char*)d_ws;
    __bf16* xb  = (__bf16*)ws;                              // [0,16M): xb, then VT after QKV GEMM
    __bf16* wb  = (__bf16*)(ws + (size_t)16777216);         // [16M,24M): 4 weights bf16
    __bf16* qkv = (__bf16*)(ws + (size_t)25165824);         // [24M,72M): Q,K,V planes
    __bf16* yb  = (__bf16*)(ws + (size_t)75497472);         // [72M,88M): attn out bf16

    cvt_kernel<<<dim3(GM * GK / 8 / 256), 256, 0, stream>>>(x, xb, GM * GK / 8);
    cvt4_kernel<<<dim3(CC * CC / 8 / 256, 1, 4), 256, 0, stream>>>(wq, wk, wv, wo, wb);
    gemm_nt<<<dim3(GN / 128, GM / 128, 3), 256, 0, stream>>>(
        xb, wb, qkv, nullptr, (size_t)CC * CC, (size_t)GM * GN);
    // V plane -> VT [1024][8192]; xb region is dead now, reuse it
    transpose_kernel<<<dim3(GM / 64, GN / 64), 256, 0, stream>>>(
        qkv + (size_t)2 * GM * GN, xb);
    // grid: x = bh (64), y = fold-pair index (16); every block = 33 strip-iters
    attn_kernel<<<dim3(BB * HH, 16), 256, 0, stream>>>(
        qkv, qkv + (size_t)GM * GN, xb, yb);
    gemm_nt<<<dim3(GN / 128, GM / 128, 1), 256, 0, stream>>>(
        yb, wb + (size_t)3 * CC * CC, nullptr, out, 0, 0);
}